// Round 4
// 651.717 us; speedup vs baseline: 1.0005x; 1.0005x over previous
//
#include <hip/hip_runtime.h>

#define T_STEPS 1000
#define DT 0.1f
#define HIDDEN 128
#define N_AGENTS 1024

typedef float v2f __attribute__((ext_vector_type(2)));

// tanh(x) = 1 - 2/(exp(2x)+1); exact at +/-inf, ~1e-7 rel error.
__device__ __forceinline__ float tanh_fast(float x) {
    float e = __expf(2.0f * x);
    return 1.0f - 2.0f * __builtin_amdgcn_rcpf(e + 1.0f);
}

// Opaque 8B load (R13-R18 proven residency mechanism).
__device__ __forceinline__ v2f opaque_load8(const float* p) {
    v2f v;
    asm volatile("global_load_dwordx2 %0, %1, off\n\ts_waitcnt vmcnt(0)"
                 : "=v"(v)
                 : "v"((unsigned long long)(uintptr_t)p)
                 : "memory");
    return v;
}

__device__ __forceinline__ float uniformf(float v) {
    return __builtin_bit_cast(float,
        __builtin_amdgcn_readfirstlane(__builtin_bit_cast(int, v)));
}

// 64-lane sum on the VALU pipe via DPP row ops (R11-R18 verified).
__device__ __forceinline__ float wave_sum_dpp(float x) {
    float t;
    #define DPPADD(ctrl, rmask)                                              \
        t = __builtin_bit_cast(float, __builtin_amdgcn_update_dpp(           \
                0, __builtin_bit_cast(int, x), ctrl, rmask, 0xf, false));    \
        x += t;
    DPPADD(0x111, 0xf)
    DPPADD(0x112, 0xf)
    DPPADD(0x114, 0xf)
    DPPADD(0x118, 0xf)
    DPPADD(0x142, 0xa)
    DPPADD(0x143, 0xc)
    #undef DPPADD
    return __builtin_bit_cast(float,
        __builtin_amdgcn_readlane(__builtin_bit_cast(int, x), 63));
}

// Pre-pack W1 into component-paired layout (R14-R18 verified).
__global__ void pack_kernel(const float* __restrict__ W1,
                            float* __restrict__ pw) {
    const int row = blockIdx.x;     // 128
    const int a   = threadIdx.x;    // 32
    const float* rp = W1 + row * 128;
    float* out = pw + row * 128;
    out[2*a]          = rp[3*a];
    out[2*a + 1]      = rp[3*a + 1];
    out[64 + 2*a]     = rp[3*a + 2];
    out[64 + 2*a + 1] = rp[96 + a];
}

// R23 = ROUND-0 BASELINE (652us, absmax 0.0) VERBATIM + ONE delta:
// consumer wave at s_setprio(1). Bisection anchor: R20-R22 all failed with
// deterministic ~2-ulp errors sharing deltas {e4buf re-read, zero-init
// removal, setprio}. setprio provably cannot change numerics (all cross-wave
// exchange is barrier-separated; priority cannot cross s_barrier; single-wave
// rounding unchanged). PASS here => bug is in {3}/{4}; FAIL => baseline sync
// is timing-fragile and setprio is quarantined too.
__global__ __launch_bounds__(128)
__attribute__((amdgpu_waves_per_eu(2, 2)))
void sim_kernel(const float* __restrict__ target_pos,
                const float* __restrict__ logsigma,
                const float* __restrict__ x_inits,
                const float* __restrict__ pw,
                const float* __restrict__ b1,
                const float* __restrict__ W2,
                const float* __restrict__ b2,
                float2* __restrict__ ws) {
    const int agent = blockIdx.x;
    const int tid  = threadIdx.x;   // 0..127
    const int h    = tid >> 6;      // 0 = consumer, 1 = producer
    const int lane = tid & 63;
    const int rowA = lane;
    const int rowB = lane + 64;

    __shared__ float2 part1[32][64];        // h=1 -> h=0 partial ring
    __shared__ float4 e4buf[16];            // state ring, 16-deep

    if (h == 0) __builtin_amdgcn_s_setprio(1);   // R23: the single delta

    const float tx0 = uniformf(target_pos[0]), ty0 = uniformf(target_pos[1]);
    const float tx1 = uniformf(target_pos[2]), ty1 = uniformf(target_pos[3]);
    const float tx2 = uniformf(target_pos[4]), ty2 = uniformf(target_pos[5]);
    const float is0 = uniformf(1.0f / expf(logsigma[0]));
    const float is1 = uniformf(1.0f / expf(logsigma[1]));
    const float is2 = uniformf(1.0f / expf(logsigma[2]));

    // Paired weights for ages 16h..16h+15, rows A and B: 64 v2f pinned.
    v2f WxyA[16], WzcA[16], WxyB[16], WzcB[16];
    {
        const float* baseA = pw + rowA * 128;
        const float* baseB = pw + rowB * 128;
        #pragma unroll
        for (int i = 0; i < 16; ++i) {
            WxyA[i] = opaque_load8(baseA + 32 * h + 2 * i);
            WzcA[i] = opaque_load8(baseA + 64 + 32 * h + 2 * i);
            WxyB[i] = opaque_load8(baseB + 32 * h + 2 * i);
            WzcB[i] = opaque_load8(baseB + 64 + 32 * h + 2 * i);
        }
    }
    const float b1A = b1[rowA], b1B = b1[rowB];
    const float w20A = W2[rowA], w20B = W2[rowB];
    const float w21A = W2[HIDDEN + rowA], w21B = W2[HIDDEN + rowB];
    const float b2x = uniformf(b2[0]), b2y = uniformf(b2[1]);

    auto conc = [&](float px, float py) {
        float dx0 = px - tx0, dy0 = py - ty0;
        float dx1 = px - tx1, dy1 = py - ty1;
        float dx2 = px - tx2, dy2 = py - ty2;
        float cc  = is0 * __expf(-(dx0*dx0 + dy0*dy0) * is0);
        cc       += is1 * __expf(-(dx1*dx1 + dy1*dy1) * is1);
        cc       += is2 * __expf(-(dx2*dx2 + dy2*dy2) * is2);
        return cc;
    };

    float x  = uniformf(x_inits[3 * agent]);
    float y  = uniformf(x_inits[3 * agent + 1]);
    float th = uniformf(x_inits[3 * agent + 2]);
    float c  = conc(x, y);

    if (h == 0) {
        // ---------------- consumer wave ----------------
        v2f RA[16], RB[16];
        {   // seed slot s: sum_{k=s..15} W[k]·e(0)
            v2f exy0 = {x, y}, ezc0 = {th, c};
            v2f aA = {0.f,0.f}, aB = {0.f,0.f};
            #pragma unroll
            for (int k = 15; k >= 0; --k) {
                aA = WxyA[k]*exy0 + aA;  aA = WzcA[k]*ezc0 + aA;
                aB = WxyB[k]*exy0 + aB;  aB = WzcB[k]*ezc0 + aB;
                RA[k] = aA;  RB[k] = aB;
            }
            if (lane == 0) {
                float4 e0 = make_float4(x, y, th, c);
                #pragma unroll
                for (int m = 9; m < 16; ++m) e4buf[m] = e0;
                e4buf[0] = e0;
            }
        }
        __syncthreads();              // seed barrier (both waves)
        float2 pl = part1[0][lane];   // partial_1 for step 0
        v2f es_xy[4], es_zc[4];
        float S_c = 0.f, S_u = 0.f;

        auto h0_step = [&](int j, int s16) {
            float hA = fmaxf((RA[j].x + RA[j].y) + pl.x + b1A, 0.f);
            float hB = fmaxf((RB[j].x + RB[j].y) + pl.y + b1B, 0.f);
            RA[j] = (v2f){0.f, 0.f};   // recycle slot for step j+16
            RB[j] = (v2f){0.f, 0.f};
            float s0 = wave_sum_dpp(fmaf(w20A, hA, w20B * hB));
            float s1 = wave_sum_dpp(fmaf(w21A, hA, w21B * hB));
            float v  = tanh_fast(s0 + b2x);
            float wv = tanh_fast(s1 + b2y);
            S_u += v * v + wv * wv;
            float sn = __sinf(th), cs = __cosf(th);
            float dv = DT * v;
            x  = fmaf(dv, cs, x);
            y  = fmaf(dv, sn, y);
            th = fmaf(DT, wv, th);
            c  = conc(x, y);
            S_c += c;
            if (lane == 0) e4buf[(j + 1) & 15] = make_float4(x, y, th, c);
            v2f exy = {x, y}, ezc = {th, c};
            es_xy[j & 3] = exy;  es_zc[j & 3] = ezc;
            // urgent taps: k <= 2 - (j&3)
            #pragma unroll
            for (int k = 0; k < 3; ++k) {
                if (k <= 2 - (j & 3)) {
                    const int m = (j + 1 + k) & 15;
                    RA[m] = WxyA[k]*exy + RA[m];  RA[m] = WzcA[k]*ezc + RA[m];
                    RB[m] = WxyB[k]*exy + RB[m];  RB[m] = WzcB[k]*ezc + RB[m];
                }
            }
            pl = part1[(s16 + j + 1) & 31][lane];
        };
        auto h0_batch = [&](int q) {   // lazy taps of states e(.+4q+1..+4)
            #pragma unroll
            for (int kk = 0; kk < 16; ++kk) {
                #pragma unroll
                for (int i = 0; i < 4; ++i) {
                    if (kk >= 3 - i) {
                        const int m = (4*q + i + 1 + kk) & 15;
                        RA[m] = WxyA[kk]*es_xy[i] + RA[m];
                        RA[m] = WzcA[kk]*es_zc[i] + RA[m];
                        RB[m] = WxyB[kk]*es_xy[i] + RB[m];
                        RB[m] = WzcB[kk]*es_zc[i] + RB[m];
                    }
                }
            }
        };

        #pragma unroll 1
        for (int b = 0; b < 62; ++b) {
            const int s16 = (b & 1) << 4;
            __syncthreads();
            #pragma unroll
            for (int j = 0; j < 4; ++j) h0_step(j, s16);
            h0_batch(0);
            #pragma unroll
            for (int j = 4; j < 8; ++j) h0_step(j, s16);
            h0_batch(1);
            __syncthreads();
            #pragma unroll
            for (int j = 8; j < 12; ++j) h0_step(j, s16);
            h0_batch(2);
            #pragma unroll
            for (int j = 12; j < 16; ++j) h0_step(j, s16);
            h0_batch(3);
        }
        // remainder: steps 992..999 (b=62, s16=0)
        __syncthreads();
        #pragma unroll
        for (int j = 0; j < 4; ++j) h0_step(j, 0);
        h0_batch(0);
        #pragma unroll
        for (int j = 4; j < 8; ++j) h0_step(j, 0);

        if (lane == 0) ws[agent] = make_float2(S_c, S_u);
    } else {
        // ---------------- producer wave ----------------
        v2f PA[20], PB[20];
        {   // ring seed: PA[idx] = sum_{k=idx+1..15} W[k]·e(0), idx 0..14
            v2f exy0 = {x, y}, ezc0 = {th, c};
            #pragma unroll
            for (int i = 15; i < 20; ++i) { PA[i] = (v2f){0.f,0.f}; PB[i] = (v2f){0.f,0.f}; }
            v2f aA = {0.f,0.f}, aB = {0.f,0.f};
            #pragma unroll
            for (int k = 15; k >= 1; --k) {
                aA = WxyA[k]*exy0 + aA;  aA = WzcA[k]*ezc0 + aA;
                aB = WxyB[k]*exy0 + aB;  aB = WzcB[k]*ezc0 + aB;
                PA[k-1] = aA;  PB[k-1] = aB;
            }
            // part1 prefill s=0..8: full 16-tap sum
            v2f fA = WxyA[0]*exy0 + aA;  fA = WzcA[0]*ezc0 + fA;
            v2f fB = WxyB[0]*exy0 + aB;  fB = WzcB[0]*ezc0 + fB;
            float2 full = make_float2(fA.x + fA.y, fB.x + fB.y);
            #pragma unroll
            for (int s = 0; s <= 8; ++s) part1[s][lane] = full;
        }
        __syncthreads();              // seed barrier

        auto h1_batch = [&](int n, int b1w) {
            // read 4 states e(16b-7+4n .. +3 more): e4buf[(9+4n+i)&15]
            v2f pxy[4], pzc[4];
            #pragma unroll
            for (int i = 0; i < 4; ++i) {
                float4 e = e4buf[(9 + 4*n + i) & 15];
                pxy[i] = (v2f){e.x, e.y};
                pzc[i] = (v2f){e.z, e.w};
            }
            // k-outer push: each weight fetched once, used 4x
            #pragma unroll
            for (int kk = 0; kk < 16; ++kk) {
                #pragma unroll
                for (int i = 0; i < 4; ++i) {
                    const int idx = i + kk;
                    PA[idx] = WxyA[kk]*pxy[i] + PA[idx];
                    PA[idx] = WzcA[kk]*pzc[i] + PA[idx];
                    PB[idx] = WxyB[kk]*pxy[i] + PB[idx];
                    PB[idx] = WzcB[kk]*pzc[i] + PB[idx];
                }
            }
            // ship 4 completed partials: s = 16b + 9+4n + i
            #pragma unroll
            for (int i = 0; i < 4; ++i) {
                part1[(b1w * 16 + 9 + 4*n + i) & 31][lane] =
                    make_float2(PA[i].x + PA[i].y, PB[i].x + PB[i].y);
            }
            // rotate by 4
            #pragma unroll
            for (int i = 0; i < 16; ++i) { PA[i] = PA[i+4]; PB[i] = PB[i+4]; }
            #pragma unroll
            for (int i = 16; i < 20; ++i) { PA[i] = (v2f){0.f,0.f}; PB[i] = (v2f){0.f,0.f}; }
        };

        #pragma unroll 1
        for (int b = 0; b < 62; ++b) {
            const int b1w = b & 1;
            __syncthreads();
            h1_batch(0, b1w);
            h1_batch(1, b1w);
            __syncthreads();
            h1_batch(2, b1w);
            h1_batch(3, b1w);
        }
        __syncthreads();   // remainder barrier (match h0); nothing to ship
    }
}

__global__ void reduce_kernel(const float2* __restrict__ ws,
                              float* __restrict__ out) {
    const int tid = threadIdx.x;  // 256 threads
    float sc = 0.f, su = 0.f;
    for (int i = tid; i < N_AGENTS; i += 256) {
        float2 v = ws[i];
        sc += v.x;
        su += v.y;
    }
    #pragma unroll
    for (int off = 32; off > 0; off >>= 1) {
        sc += __shfl_xor(sc, off);
        su += __shfl_xor(su, off);
    }
    __shared__ float2 partw[4];
    int wave = tid >> 6;
    if ((tid & 63) == 0) partw[wave] = make_float2(sc, su);
    __syncthreads();
    if (tid == 0) {
        float SC = partw[0].x + partw[1].x + partw[2].x + partw[3].x;
        float SU = partw[0].y + partw[1].y + partw[2].y + partw[3].y;
        const float invNT  = 1.0f / (float)(N_AGENTS * T_STEPS);
        const float invNT2 = 1.0f / (float)(N_AGENTS * T_STEPS * 2);
        out[0] = -SC * invNT + SU * invNT2;
    }
}

extern "C" void kernel_launch(void* const* d_in, const int* in_sizes, int n_in,
                              void* d_out, int out_size, void* d_ws, size_t ws_size,
                              hipStream_t stream) {
    const float* target_pos = (const float*)d_in[0];
    const float* logsigma   = (const float*)d_in[1];
    const float* x_inits    = (const float*)d_in[2];
    const float* W1         = (const float*)d_in[3];
    const float* b1         = (const float*)d_in[4];
    const float* W2         = (const float*)d_in[5];
    const float* b2         = (const float*)d_in[6];

    float*  pw   = (float*)d_ws;                          // 64 KB packed W1
    float2* sums = (float2*)((char*)d_ws + 64 * 1024);    // per-agent sums

    pack_kernel<<<HIDDEN, 32, 0, stream>>>(W1, pw);
    sim_kernel<<<N_AGENTS, 128, 0, stream>>>(target_pos, logsigma, x_inits,
                                             pw, b1, W2, b2, sums);
    reduce_kernel<<<1, 256, 0, stream>>>(sums, (float*)d_out);
}

// Round 5
// 651.037 us; speedup vs baseline: 1.0016x; 1.0010x over previous
//
#include <hip/hip_runtime.h>

#define T_STEPS 1000
#define DT 0.1f
#define HIDDEN 128
#define N_AGENTS 1024

typedef float v2f __attribute__((ext_vector_type(2)));

// tanh(x) = 1 - 2/(exp(2x)+1); exact at +/-inf, ~1e-7 rel error.
__device__ __forceinline__ float tanh_fast(float x) {
    float e = __expf(2.0f * x);
    return 1.0f - 2.0f * __builtin_amdgcn_rcpf(e + 1.0f);
}

// Opaque 8B load (R13-R18 proven residency mechanism).
__device__ __forceinline__ v2f opaque_load8(const float* p) {
    v2f v;
    asm volatile("global_load_dwordx2 %0, %1, off\n\ts_waitcnt vmcnt(0)"
                 : "=v"(v)
                 : "v"((unsigned long long)(uintptr_t)p)
                 : "memory");
    return v;
}

__device__ __forceinline__ float uniformf(float v) {
    return __builtin_bit_cast(float,
        __builtin_amdgcn_readfirstlane(__builtin_bit_cast(int, v)));
}

// 64-lane sum on the VALU pipe via DPP row ops (R11-R18 verified).
__device__ __forceinline__ float wave_sum_dpp(float x) {
    float t;
    #define DPPADD(ctrl, rmask)                                              \
        t = __builtin_bit_cast(float, __builtin_amdgcn_update_dpp(           \
                0, __builtin_bit_cast(int, x), ctrl, rmask, 0xf, false));    \
        x += t;
    DPPADD(0x111, 0xf)
    DPPADD(0x112, 0xf)
    DPPADD(0x114, 0xf)
    DPPADD(0x118, 0xf)
    DPPADD(0x142, 0xa)
    DPPADD(0x143, 0xc)
    #undef DPPADD
    return __builtin_bit_cast(float,
        __builtin_amdgcn_readlane(__builtin_bit_cast(int, x), 63));
}

// Pre-pack W1 into component-paired layout (R14-R18 verified).
__global__ void pack_kernel(const float* __restrict__ W1,
                            float* __restrict__ pw) {
    const int row = blockIdx.x;     // 128
    const int a   = threadIdx.x;    // 32
    const float* rp = W1 + row * 128;
    float* out = pw + row * 128;
    out[2*a]          = rp[3*a];
    out[2*a + 1]      = rp[3*a + 1];
    out[64 + 2*a]     = rp[3*a + 2];
    out[64 + 2*a + 1] = rp[96 + a];
}

// R24 = R23 (652us anchor, absmax 0.0) + ONE delta: consumer slot-zeroing
// removed. Recycled slot 4q+r's first writer is batch-q tap (i=3,kk=12+r)
// (kk-outer order; urgent taps never target slots 4q..4q+3 post-consume)
// -> that tap becomes a pk_mul overwrite. fma(a,b,0)==a*b bitwise (mod -0,
// which dies in subsequent nonzero adds). Producer zeroing UNTOUCHED;
// h0_batch keeps baseline es_xy/es_zc registers (no e4buf re-read).
// If this fails: even mul-for-fma(..,0) substitution perturbs codegen FP
// -> kernel is FP-frozen at this structure (bit-exactness contract).
__global__ __launch_bounds__(128)
__attribute__((amdgpu_waves_per_eu(2, 2)))
void sim_kernel(const float* __restrict__ target_pos,
                const float* __restrict__ logsigma,
                const float* __restrict__ x_inits,
                const float* __restrict__ pw,
                const float* __restrict__ b1,
                const float* __restrict__ W2,
                const float* __restrict__ b2,
                float2* __restrict__ ws) {
    const int agent = blockIdx.x;
    const int tid  = threadIdx.x;   // 0..127
    const int h    = tid >> 6;      // 0 = consumer, 1 = producer
    const int lane = tid & 63;
    const int rowA = lane;
    const int rowB = lane + 64;

    __shared__ float2 part1[32][64];        // h=1 -> h=0 partial ring
    __shared__ float4 e4buf[16];            // state ring, 16-deep

    if (h == 0) __builtin_amdgcn_s_setprio(1);   // R23-proven safe/neutral

    const float tx0 = uniformf(target_pos[0]), ty0 = uniformf(target_pos[1]);
    const float tx1 = uniformf(target_pos[2]), ty1 = uniformf(target_pos[3]);
    const float tx2 = uniformf(target_pos[4]), ty2 = uniformf(target_pos[5]);
    const float is0 = uniformf(1.0f / expf(logsigma[0]));
    const float is1 = uniformf(1.0f / expf(logsigma[1]));
    const float is2 = uniformf(1.0f / expf(logsigma[2]));

    // Paired weights for ages 16h..16h+15, rows A and B: 64 v2f pinned.
    v2f WxyA[16], WzcA[16], WxyB[16], WzcB[16];
    {
        const float* baseA = pw + rowA * 128;
        const float* baseB = pw + rowB * 128;
        #pragma unroll
        for (int i = 0; i < 16; ++i) {
            WxyA[i] = opaque_load8(baseA + 32 * h + 2 * i);
            WzcA[i] = opaque_load8(baseA + 64 + 32 * h + 2 * i);
            WxyB[i] = opaque_load8(baseB + 32 * h + 2 * i);
            WzcB[i] = opaque_load8(baseB + 64 + 32 * h + 2 * i);
        }
    }
    const float b1A = b1[rowA], b1B = b1[rowB];
    const float w20A = W2[rowA], w20B = W2[rowB];
    const float w21A = W2[HIDDEN + rowA], w21B = W2[HIDDEN + rowB];
    const float b2x = uniformf(b2[0]), b2y = uniformf(b2[1]);

    auto conc = [&](float px, float py) {
        float dx0 = px - tx0, dy0 = py - ty0;
        float dx1 = px - tx1, dy1 = py - ty1;
        float dx2 = px - tx2, dy2 = py - ty2;
        float cc  = is0 * __expf(-(dx0*dx0 + dy0*dy0) * is0);
        cc       += is1 * __expf(-(dx1*dx1 + dy1*dy1) * is1);
        cc       += is2 * __expf(-(dx2*dx2 + dy2*dy2) * is2);
        return cc;
    };

    float x  = uniformf(x_inits[3 * agent]);
    float y  = uniformf(x_inits[3 * agent + 1]);
    float th = uniformf(x_inits[3 * agent + 2]);
    float c  = conc(x, y);

    if (h == 0) {
        // ---------------- consumer wave ----------------
        v2f RA[16], RB[16];
        {   // seed slot s: sum_{k=s..15} W[k]·e(0)
            v2f exy0 = {x, y}, ezc0 = {th, c};
            v2f aA = {0.f,0.f}, aB = {0.f,0.f};
            #pragma unroll
            for (int k = 15; k >= 0; --k) {
                aA = WxyA[k]*exy0 + aA;  aA = WzcA[k]*ezc0 + aA;
                aB = WxyB[k]*exy0 + aB;  aB = WzcB[k]*ezc0 + aB;
                RA[k] = aA;  RB[k] = aB;
            }
            if (lane == 0) {
                float4 e0 = make_float4(x, y, th, c);
                #pragma unroll
                for (int m = 9; m < 16; ++m) e4buf[m] = e0;
                e4buf[0] = e0;
            }
        }
        __syncthreads();              // seed barrier (both waves)
        float2 pl = part1[0][lane];   // partial_1 for step 0
        v2f es_xy[4], es_zc[4];
        float S_c = 0.f, S_u = 0.f;

        auto h0_step = [&](int j, int s16) {
            float hA = fmaxf((RA[j].x + RA[j].y) + pl.x + b1A, 0.f);
            float hB = fmaxf((RB[j].x + RB[j].y) + pl.y + b1B, 0.f);
            // R24: no slot zeroing -- batch (i==3,kk>=12) tap overwrites.
            float s0 = wave_sum_dpp(fmaf(w20A, hA, w20B * hB));
            float s1 = wave_sum_dpp(fmaf(w21A, hA, w21B * hB));
            float v  = tanh_fast(s0 + b2x);
            float wv = tanh_fast(s1 + b2y);
            S_u += v * v + wv * wv;
            float sn = __sinf(th), cs = __cosf(th);
            float dv = DT * v;
            x  = fmaf(dv, cs, x);
            y  = fmaf(dv, sn, y);
            th = fmaf(DT, wv, th);
            c  = conc(x, y);
            S_c += c;
            if (lane == 0) e4buf[(j + 1) & 15] = make_float4(x, y, th, c);
            v2f exy = {x, y}, ezc = {th, c};
            es_xy[j & 3] = exy;  es_zc[j & 3] = ezc;
            // urgent taps: k <= 2 - (j&3)
            #pragma unroll
            for (int k = 0; k < 3; ++k) {
                if (k <= 2 - (j & 3)) {
                    const int m = (j + 1 + k) & 15;
                    RA[m] = WxyA[k]*exy + RA[m];  RA[m] = WzcA[k]*ezc + RA[m];
                    RB[m] = WxyB[k]*exy + RB[m];  RB[m] = WzcB[k]*ezc + RB[m];
                }
            }
            pl = part1[(s16 + j + 1) & 31][lane];
        };
        auto h0_batch = [&](int q) {   // lazy taps of states e(.+4q+1..+4)
            #pragma unroll
            for (int kk = 0; kk < 16; ++kk) {
                #pragma unroll
                for (int i = 0; i < 4; ++i) {
                    if (kk >= 3 - i) {
                        const int m = (4*q + i + 1 + kk) & 15;
                        if (i == 3 && kk >= 12) {
                            // first write since consume -> overwrite
                            RA[m] = WxyA[kk]*es_xy[i];
                            RA[m] = WzcA[kk]*es_zc[i] + RA[m];
                            RB[m] = WxyB[kk]*es_xy[i];
                            RB[m] = WzcB[kk]*es_zc[i] + RB[m];
                        } else {
                            RA[m] = WxyA[kk]*es_xy[i] + RA[m];
                            RA[m] = WzcA[kk]*es_zc[i] + RA[m];
                            RB[m] = WxyB[kk]*es_xy[i] + RB[m];
                            RB[m] = WzcB[kk]*es_zc[i] + RB[m];
                        }
                    }
                }
            }
        };

        #pragma unroll 1
        for (int b = 0; b < 62; ++b) {
            const int s16 = (b & 1) << 4;
            __syncthreads();
            #pragma unroll
            for (int j = 0; j < 4; ++j) h0_step(j, s16);
            h0_batch(0);
            #pragma unroll
            for (int j = 4; j < 8; ++j) h0_step(j, s16);
            h0_batch(1);
            __syncthreads();
            #pragma unroll
            for (int j = 8; j < 12; ++j) h0_step(j, s16);
            h0_batch(2);
            #pragma unroll
            for (int j = 12; j < 16; ++j) h0_step(j, s16);
            h0_batch(3);
        }
        // remainder: steps 992..999 (b=62, s16=0); consumed slots never
        // re-read after kernel end, so no recycling needed.
        __syncthreads();
        #pragma unroll
        for (int j = 0; j < 4; ++j) h0_step(j, 0);
        h0_batch(0);
        #pragma unroll
        for (int j = 4; j < 8; ++j) h0_step(j, 0);

        if (lane == 0) ws[agent] = make_float2(S_c, S_u);
    } else {
        // ---------------- producer wave (UNCHANGED from R23/baseline) ----
        v2f PA[20], PB[20];
        {   // ring seed: PA[idx] = sum_{k=idx+1..15} W[k]·e(0), idx 0..14
            v2f exy0 = {x, y}, ezc0 = {th, c};
            #pragma unroll
            for (int i = 15; i < 20; ++i) { PA[i] = (v2f){0.f,0.f}; PB[i] = (v2f){0.f,0.f}; }
            v2f aA = {0.f,0.f}, aB = {0.f,0.f};
            #pragma unroll
            for (int k = 15; k >= 1; --k) {
                aA = WxyA[k]*exy0 + aA;  aA = WzcA[k]*ezc0 + aA;
                aB = WxyB[k]*exy0 + aB;  aB = WzcB[k]*ezc0 + aB;
                PA[k-1] = aA;  PB[k-1] = aB;
            }
            // part1 prefill s=0..8: full 16-tap sum
            v2f fA = WxyA[0]*exy0 + aA;  fA = WzcA[0]*ezc0 + fA;
            v2f fB = WxyB[0]*exy0 + aB;  fB = WzcB[0]*ezc0 + fB;
            float2 full = make_float2(fA.x + fA.y, fB.x + fB.y);
            #pragma unroll
            for (int s = 0; s <= 8; ++s) part1[s][lane] = full;
        }
        __syncthreads();              // seed barrier

        auto h1_batch = [&](int n, int b1w) {
            // read 4 states e(16b-7+4n .. +3 more): e4buf[(9+4n+i)&15]
            v2f pxy[4], pzc[4];
            #pragma unroll
            for (int i = 0; i < 4; ++i) {
                float4 e = e4buf[(9 + 4*n + i) & 15];
                pxy[i] = (v2f){e.x, e.y};
                pzc[i] = (v2f){e.z, e.w};
            }
            // k-outer push: each weight fetched once, used 4x
            #pragma unroll
            for (int kk = 0; kk < 16; ++kk) {
                #pragma unroll
                for (int i = 0; i < 4; ++i) {
                    const int idx = i + kk;
                    PA[idx] = WxyA[kk]*pxy[i] + PA[idx];
                    PA[idx] = WzcA[kk]*pzc[i] + PA[idx];
                    PB[idx] = WxyB[kk]*pxy[i] + PB[idx];
                    PB[idx] = WzcB[kk]*pzc[i] + PB[idx];
                }
            }
            // ship 4 completed partials: s = 16b + 9+4n + i
            #pragma unroll
            for (int i = 0; i < 4; ++i) {
                part1[(b1w * 16 + 9 + 4*n + i) & 31][lane] =
                    make_float2(PA[i].x + PA[i].y, PB[i].x + PB[i].y);
            }
            // rotate by 4
            #pragma unroll
            for (int i = 0; i < 16; ++i) { PA[i] = PA[i+4]; PB[i] = PB[i+4]; }
            #pragma unroll
            for (int i = 16; i < 20; ++i) { PA[i] = (v2f){0.f,0.f}; PB[i] = (v2f){0.f,0.f}; }
        };

        #pragma unroll 1
        for (int b = 0; b < 62; ++b) {
            const int b1w = b & 1;
            __syncthreads();
            h1_batch(0, b1w);
            h1_batch(1, b1w);
            __syncthreads();
            h1_batch(2, b1w);
            h1_batch(3, b1w);
        }
        __syncthreads();   // remainder barrier (match h0); nothing to ship
    }
}

__global__ void reduce_kernel(const float2* __restrict__ ws,
                              float* __restrict__ out) {
    const int tid = threadIdx.x;  // 256 threads
    float sc = 0.f, su = 0.f;
    for (int i = tid; i < N_AGENTS; i += 256) {
        float2 v = ws[i];
        sc += v.x;
        su += v.y;
    }
    #pragma unroll
    for (int off = 32; off > 0; off >>= 1) {
        sc += __shfl_xor(sc, off);
        su += __shfl_xor(su, off);
    }
    __shared__ float2 partw[4];
    int wave = tid >> 6;
    if ((tid & 63) == 0) partw[wave] = make_float2(sc, su);
    __syncthreads();
    if (tid == 0) {
        float SC = partw[0].x + partw[1].x + partw[2].x + partw[3].x;
        float SU = partw[0].y + partw[1].y + partw[2].y + partw[3].y;
        const float invNT  = 1.0f / (float)(N_AGENTS * T_STEPS);
        const float invNT2 = 1.0f / (float)(N_AGENTS * T_STEPS * 2);
        out[0] = -SC * invNT + SU * invNT2;
    }
}

extern "C" void kernel_launch(void* const* d_in, const int* in_sizes, int n_in,
                              void* d_out, int out_size, void* d_ws, size_t ws_size,
                              hipStream_t stream) {
    const float* target_pos = (const float*)d_in[0];
    const float* logsigma   = (const float*)d_in[1];
    const float* x_inits    = (const float*)d_in[2];
    const float* W1         = (const float*)d_in[3];
    const float* b1         = (const float*)d_in[4];
    const float* W2         = (const float*)d_in[5];
    const float* b2         = (const float*)d_in[6];

    float*  pw   = (float*)d_ws;                          // 64 KB packed W1
    float2* sums = (float2*)((char*)d_ws + 64 * 1024);    // per-agent sums

    pack_kernel<<<HIDDEN, 32, 0, stream>>>(W1, pw);
    sim_kernel<<<N_AGENTS, 128, 0, stream>>>(target_pos, logsigma, x_inits,
                                             pw, b1, W2, b2, sums);
    reduce_kernel<<<1, 256, 0, stream>>>(sums, (float*)d_out);
}

// Round 6
// 632.293 us; speedup vs baseline: 1.0312x; 1.0296x over previous
//
#include <hip/hip_runtime.h>

#define T_STEPS 1000
#define DT 0.1f
#define HIDDEN 128
#define N_AGENTS 1024

typedef float v2f __attribute__((ext_vector_type(2)));

// tanh(x) = 1 - 2/(exp(2x)+1); exact at +/-inf, ~1e-7 rel error.
__device__ __forceinline__ float tanh_fast(float x) {
    float e = __expf(2.0f * x);
    return 1.0f - 2.0f * __builtin_amdgcn_rcpf(e + 1.0f);
}

// Opaque 8B load (R13-R18 proven residency mechanism).
__device__ __forceinline__ v2f opaque_load8(const float* p) {
    v2f v;
    asm volatile("global_load_dwordx2 %0, %1, off\n\ts_waitcnt vmcnt(0)"
                 : "=v"(v)
                 : "v"((unsigned long long)(uintptr_t)p)
                 : "memory");
    return v;
}

__device__ __forceinline__ float uniformf(float v) {
    return __builtin_bit_cast(float,
        __builtin_amdgcn_readfirstlane(__builtin_bit_cast(int, v)));
}

// R25: DUAL fused DPP reduction. The builtin update_dpp(old=0,..)+add form
// defeats GCNDPPCombine (explicit old operand) -> 2 instr/stage. Hand-fused
// v_add_f32_dpp = 1 instr/stage, bitwise-identical adds in identical order:
//  - row_shr stages: bound_ctrl:0 (invalid lanes read 0) == builtin's t=old=0.
//  - bcast stages: row_mask-unwritten dst rows keep x == builtin's x+=0.
// The two independent sums interleave so each partner op provides the
// VALU-write->DPP-read wait states; s_nop guards cover stage boundaries and
// block entry (preceding fma writes %0/%1) / exit (readlane follows).
__device__ __forceinline__ void wave_sum2_dpp(float& a, float& b) {
    asm volatile(
        "s_nop 1\n\t"
        "v_add_f32_dpp %0, %0, %0 row_shr:1 row_mask:0xf bank_mask:0xf bound_ctrl:0\n\t"
        "v_add_f32_dpp %1, %1, %1 row_shr:1 row_mask:0xf bank_mask:0xf bound_ctrl:0\n\t"
        "s_nop 0\n\t"
        "v_add_f32_dpp %0, %0, %0 row_shr:2 row_mask:0xf bank_mask:0xf bound_ctrl:0\n\t"
        "v_add_f32_dpp %1, %1, %1 row_shr:2 row_mask:0xf bank_mask:0xf bound_ctrl:0\n\t"
        "s_nop 0\n\t"
        "v_add_f32_dpp %0, %0, %0 row_shr:4 row_mask:0xf bank_mask:0xf bound_ctrl:0\n\t"
        "v_add_f32_dpp %1, %1, %1 row_shr:4 row_mask:0xf bank_mask:0xf bound_ctrl:0\n\t"
        "s_nop 0\n\t"
        "v_add_f32_dpp %0, %0, %0 row_shr:8 row_mask:0xf bank_mask:0xf bound_ctrl:0\n\t"
        "v_add_f32_dpp %1, %1, %1 row_shr:8 row_mask:0xf bank_mask:0xf bound_ctrl:0\n\t"
        "s_nop 0\n\t"
        "v_add_f32_dpp %0, %0, %0 row_bcast:15 row_mask:0xa bank_mask:0xf bound_ctrl:0\n\t"
        "v_add_f32_dpp %1, %1, %1 row_bcast:15 row_mask:0xa bank_mask:0xf bound_ctrl:0\n\t"
        "s_nop 0\n\t"
        "v_add_f32_dpp %0, %0, %0 row_bcast:31 row_mask:0xc bank_mask:0xf bound_ctrl:0\n\t"
        "v_add_f32_dpp %1, %1, %1 row_bcast:31 row_mask:0xc bank_mask:0xf bound_ctrl:0\n\t"
        "s_nop 1"
        : "+v"(a), "+v"(b));
}

// Pre-pack W1 into component-paired layout (R14-R18 verified).
__global__ void pack_kernel(const float* __restrict__ W1,
                            float* __restrict__ pw) {
    const int row = blockIdx.x;     // 128
    const int a   = threadIdx.x;    // 32
    const float* rp = W1 + row * 128;
    float* out = pw + row * 128;
    out[2*a]          = rp[3*a];
    out[2*a + 1]      = rp[3*a + 1];
    out[64 + 2*a]     = rp[3*a + 2];
    out[64 + 2*a + 1] = rp[96 + a];
}

// R25 = R24 (651.0us anchor, absmax 0.0) + ONE delta: both per-step wave
// reductions through the fused dual-DPP block above. Everything else
// byte-identical to R24.
__global__ __launch_bounds__(128)
__attribute__((amdgpu_waves_per_eu(2, 2)))
void sim_kernel(const float* __restrict__ target_pos,
                const float* __restrict__ logsigma,
                const float* __restrict__ x_inits,
                const float* __restrict__ pw,
                const float* __restrict__ b1,
                const float* __restrict__ W2,
                const float* __restrict__ b2,
                float2* __restrict__ ws) {
    const int agent = blockIdx.x;
    const int tid  = threadIdx.x;   // 0..127
    const int h    = tid >> 6;      // 0 = consumer, 1 = producer
    const int lane = tid & 63;
    const int rowA = lane;
    const int rowB = lane + 64;

    __shared__ float2 part1[32][64];        // h=1 -> h=0 partial ring
    __shared__ float4 e4buf[16];            // state ring, 16-deep

    if (h == 0) __builtin_amdgcn_s_setprio(1);   // R23-proven safe/neutral

    const float tx0 = uniformf(target_pos[0]), ty0 = uniformf(target_pos[1]);
    const float tx1 = uniformf(target_pos[2]), ty1 = uniformf(target_pos[3]);
    const float tx2 = uniformf(target_pos[4]), ty2 = uniformf(target_pos[5]);
    const float is0 = uniformf(1.0f / expf(logsigma[0]));
    const float is1 = uniformf(1.0f / expf(logsigma[1]));
    const float is2 = uniformf(1.0f / expf(logsigma[2]));

    // Paired weights for ages 16h..16h+15, rows A and B: 64 v2f pinned.
    v2f WxyA[16], WzcA[16], WxyB[16], WzcB[16];
    {
        const float* baseA = pw + rowA * 128;
        const float* baseB = pw + rowB * 128;
        #pragma unroll
        for (int i = 0; i < 16; ++i) {
            WxyA[i] = opaque_load8(baseA + 32 * h + 2 * i);
            WzcA[i] = opaque_load8(baseA + 64 + 32 * h + 2 * i);
            WxyB[i] = opaque_load8(baseB + 32 * h + 2 * i);
            WzcB[i] = opaque_load8(baseB + 64 + 32 * h + 2 * i);
        }
    }
    const float b1A = b1[rowA], b1B = b1[rowB];
    const float w20A = W2[rowA], w20B = W2[rowB];
    const float w21A = W2[HIDDEN + rowA], w21B = W2[HIDDEN + rowB];
    const float b2x = uniformf(b2[0]), b2y = uniformf(b2[1]);

    auto conc = [&](float px, float py) {
        float dx0 = px - tx0, dy0 = py - ty0;
        float dx1 = px - tx1, dy1 = py - ty1;
        float dx2 = px - tx2, dy2 = py - ty2;
        float cc  = is0 * __expf(-(dx0*dx0 + dy0*dy0) * is0);
        cc       += is1 * __expf(-(dx1*dx1 + dy1*dy1) * is1);
        cc       += is2 * __expf(-(dx2*dx2 + dy2*dy2) * is2);
        return cc;
    };

    float x  = uniformf(x_inits[3 * agent]);
    float y  = uniformf(x_inits[3 * agent + 1]);
    float th = uniformf(x_inits[3 * agent + 2]);
    float c  = conc(x, y);

    if (h == 0) {
        // ---------------- consumer wave ----------------
        v2f RA[16], RB[16];
        {   // seed slot s: sum_{k=s..15} W[k]·e(0)
            v2f exy0 = {x, y}, ezc0 = {th, c};
            v2f aA = {0.f,0.f}, aB = {0.f,0.f};
            #pragma unroll
            for (int k = 15; k >= 0; --k) {
                aA = WxyA[k]*exy0 + aA;  aA = WzcA[k]*ezc0 + aA;
                aB = WxyB[k]*exy0 + aB;  aB = WzcB[k]*ezc0 + aB;
                RA[k] = aA;  RB[k] = aB;
            }
            if (lane == 0) {
                float4 e0 = make_float4(x, y, th, c);
                #pragma unroll
                for (int m = 9; m < 16; ++m) e4buf[m] = e0;
                e4buf[0] = e0;
            }
        }
        __syncthreads();              // seed barrier (both waves)
        float2 pl = part1[0][lane];   // partial_1 for step 0
        v2f es_xy[4], es_zc[4];
        float S_c = 0.f, S_u = 0.f;

        auto h0_step = [&](int j, int s16) {
            float hA = fmaxf((RA[j].x + RA[j].y) + pl.x + b1A, 0.f);
            float hB = fmaxf((RB[j].x + RB[j].y) + pl.y + b1B, 0.f);
            // R24: no slot zeroing -- batch (i==3,kk>=12) tap overwrites.
            float r0 = fmaf(w20A, hA, w20B * hB);
            float r1 = fmaf(w21A, hA, w21B * hB);
            wave_sum2_dpp(r0, r1);    // R25: fused dual reduction
            float s0 = __builtin_bit_cast(float,
                __builtin_amdgcn_readlane(__builtin_bit_cast(int, r0), 63));
            float s1 = __builtin_bit_cast(float,
                __builtin_amdgcn_readlane(__builtin_bit_cast(int, r1), 63));
            float v  = tanh_fast(s0 + b2x);
            float wv = tanh_fast(s1 + b2y);
            S_u += v * v + wv * wv;
            float sn = __sinf(th), cs = __cosf(th);
            float dv = DT * v;
            x  = fmaf(dv, cs, x);
            y  = fmaf(dv, sn, y);
            th = fmaf(DT, wv, th);
            c  = conc(x, y);
            S_c += c;
            if (lane == 0) e4buf[(j + 1) & 15] = make_float4(x, y, th, c);
            v2f exy = {x, y}, ezc = {th, c};
            es_xy[j & 3] = exy;  es_zc[j & 3] = ezc;
            // urgent taps: k <= 2 - (j&3)
            #pragma unroll
            for (int k = 0; k < 3; ++k) {
                if (k <= 2 - (j & 3)) {
                    const int m = (j + 1 + k) & 15;
                    RA[m] = WxyA[k]*exy + RA[m];  RA[m] = WzcA[k]*ezc + RA[m];
                    RB[m] = WxyB[k]*exy + RB[m];  RB[m] = WzcB[k]*ezc + RB[m];
                }
            }
            pl = part1[(s16 + j + 1) & 31][lane];
        };
        auto h0_batch = [&](int q) {   // lazy taps of states e(.+4q+1..+4)
            #pragma unroll
            for (int kk = 0; kk < 16; ++kk) {
                #pragma unroll
                for (int i = 0; i < 4; ++i) {
                    if (kk >= 3 - i) {
                        const int m = (4*q + i + 1 + kk) & 15;
                        if (i == 3 && kk >= 12) {
                            // first write since consume -> overwrite
                            RA[m] = WxyA[kk]*es_xy[i];
                            RA[m] = WzcA[kk]*es_zc[i] + RA[m];
                            RB[m] = WxyB[kk]*es_xy[i];
                            RB[m] = WzcB[kk]*es_zc[i] + RB[m];
                        } else {
                            RA[m] = WxyA[kk]*es_xy[i] + RA[m];
                            RA[m] = WzcA[kk]*es_zc[i] + RA[m];
                            RB[m] = WxyB[kk]*es_xy[i] + RB[m];
                            RB[m] = WzcB[kk]*es_zc[i] + RB[m];
                        }
                    }
                }
            }
        };

        #pragma unroll 1
        for (int b = 0; b < 62; ++b) {
            const int s16 = (b & 1) << 4;
            __syncthreads();
            #pragma unroll
            for (int j = 0; j < 4; ++j) h0_step(j, s16);
            h0_batch(0);
            #pragma unroll
            for (int j = 4; j < 8; ++j) h0_step(j, s16);
            h0_batch(1);
            __syncthreads();
            #pragma unroll
            for (int j = 8; j < 12; ++j) h0_step(j, s16);
            h0_batch(2);
            #pragma unroll
            for (int j = 12; j < 16; ++j) h0_step(j, s16);
            h0_batch(3);
        }
        // remainder: steps 992..999 (b=62, s16=0); consumed slots never
        // re-read after kernel end, so no recycling needed.
        __syncthreads();
        #pragma unroll
        for (int j = 0; j < 4; ++j) h0_step(j, 0);
        h0_batch(0);
        #pragma unroll
        for (int j = 4; j < 8; ++j) h0_step(j, 0);

        if (lane == 0) ws[agent] = make_float2(S_c, S_u);
    } else {
        // ---------------- producer wave (UNCHANGED from R23/baseline) ----
        v2f PA[20], PB[20];
        {   // ring seed: PA[idx] = sum_{k=idx+1..15} W[k]·e(0), idx 0..14
            v2f exy0 = {x, y}, ezc0 = {th, c};
            #pragma unroll
            for (int i = 15; i < 20; ++i) { PA[i] = (v2f){0.f,0.f}; PB[i] = (v2f){0.f,0.f}; }
            v2f aA = {0.f,0.f}, aB = {0.f,0.f};
            #pragma unroll
            for (int k = 15; k >= 1; --k) {
                aA = WxyA[k]*exy0 + aA;  aA = WzcA[k]*ezc0 + aA;
                aB = WxyB[k]*exy0 + aB;  aB = WzcB[k]*ezc0 + aB;
                PA[k-1] = aA;  PB[k-1] = aB;
            }
            // part1 prefill s=0..8: full 16-tap sum
            v2f fA = WxyA[0]*exy0 + aA;  fA = WzcA[0]*ezc0 + fA;
            v2f fB = WxyB[0]*exy0 + aB;  fB = WzcB[0]*ezc0 + fB;
            float2 full = make_float2(fA.x + fA.y, fB.x + fB.y);
            #pragma unroll
            for (int s = 0; s <= 8; ++s) part1[s][lane] = full;
        }
        __syncthreads();              // seed barrier

        auto h1_batch = [&](int n, int b1w) {
            // read 4 states e(16b-7+4n .. +3 more): e4buf[(9+4n+i)&15]
            v2f pxy[4], pzc[4];
            #pragma unroll
            for (int i = 0; i < 4; ++i) {
                float4 e = e4buf[(9 + 4*n + i) & 15];
                pxy[i] = (v2f){e.x, e.y};
                pzc[i] = (v2f){e.z, e.w};
            }
            // k-outer push: each weight fetched once, used 4x
            #pragma unroll
            for (int kk = 0; kk < 16; ++kk) {
                #pragma unroll
                for (int i = 0; i < 4; ++i) {
                    const int idx = i + kk;
                    PA[idx] = WxyA[kk]*pxy[i] + PA[idx];
                    PA[idx] = WzcA[kk]*pzc[i] + PA[idx];
                    PB[idx] = WxyB[kk]*pxy[i] + PB[idx];
                    PB[idx] = WzcB[kk]*pzc[i] + PB[idx];
                }
            }
            // ship 4 completed partials: s = 16b + 9+4n + i
            #pragma unroll
            for (int i = 0; i < 4; ++i) {
                part1[(b1w * 16 + 9 + 4*n + i) & 31][lane] =
                    make_float2(PA[i].x + PA[i].y, PB[i].x + PB[i].y);
            }
            // rotate by 4
            #pragma unroll
            for (int i = 0; i < 16; ++i) { PA[i] = PA[i+4]; PB[i] = PB[i+4]; }
            #pragma unroll
            for (int i = 16; i < 20; ++i) { PA[i] = (v2f){0.f,0.f}; PB[i] = (v2f){0.f,0.f}; }
        };

        #pragma unroll 1
        for (int b = 0; b < 62; ++b) {
            const int b1w = b & 1;
            __syncthreads();
            h1_batch(0, b1w);
            h1_batch(1, b1w);
            __syncthreads();
            h1_batch(2, b1w);
            h1_batch(3, b1w);
        }
        __syncthreads();   // remainder barrier (match h0); nothing to ship
    }
}

__global__ void reduce_kernel(const float2* __restrict__ ws,
                              float* __restrict__ out) {
    const int tid = threadIdx.x;  // 256 threads
    float sc = 0.f, su = 0.f;
    for (int i = tid; i < N_AGENTS; i += 256) {
        float2 v = ws[i];
        sc += v.x;
        su += v.y;
    }
    #pragma unroll
    for (int off = 32; off > 0; off >>= 1) {
        sc += __shfl_xor(sc, off);
        su += __shfl_xor(su, off);
    }
    __shared__ float2 partw[4];
    int wave = tid >> 6;
    if ((tid & 63) == 0) partw[wave] = make_float2(sc, su);
    __syncthreads();
    if (tid == 0) {
        float SC = partw[0].x + partw[1].x + partw[2].x + partw[3].x;
        float SU = partw[0].y + partw[1].y + partw[2].y + partw[3].y;
        const float invNT  = 1.0f / (float)(N_AGENTS * T_STEPS);
        const float invNT2 = 1.0f / (float)(N_AGENTS * T_STEPS * 2);
        out[0] = -SC * invNT + SU * invNT2;
    }
}

extern "C" void kernel_launch(void* const* d_in, const int* in_sizes, int n_in,
                              void* d_out, int out_size, void* d_ws, size_t ws_size,
                              hipStream_t stream) {
    const float* target_pos = (const float*)d_in[0];
    const float* logsigma   = (const float*)d_in[1];
    const float* x_inits    = (const float*)d_in[2];
    const float* W1         = (const float*)d_in[3];
    const float* b1         = (const float*)d_in[4];
    const float* W2         = (const float*)d_in[5];
    const float* b2         = (const float*)d_in[6];

    float*  pw   = (float*)d_ws;                          // 64 KB packed W1
    float2* sums = (float2*)((char*)d_ws + 64 * 1024);    // per-agent sums

    pack_kernel<<<HIDDEN, 32, 0, stream>>>(W1, pw);
    sim_kernel<<<N_AGENTS, 128, 0, stream>>>(target_pos, logsigma, x_inits,
                                             pw, b1, W2, b2, sums);
    reduce_kernel<<<1, 256, 0, stream>>>(sums, (float*)d_out);
}